// Round 7
// baseline (68.756 us; speedup 1.0000x reference)
//
#include <hip/hip_runtime.h>
#include <hip/hip_bf16.h>
#include <cstdint>

#define BATCH 256
#define DIN   512
#define D2    128
#define NQ    16
#define NC    100
#define KFC   (D2 * D2)      // 16384

#define ZKS   4              // K-splits for Z GEMM (512/4 = 128 per split)
#define ZKL   (DIN / ZKS)    // 128

#define KS    32             // K-splits for FC
#define KCH   (KFC / KS)     // 512
#define STEPS (KCH / 32)     // 16 MFMA K-steps per block

#define ZPAD  132            // Zt/Et row stride (floats): 16B-aligned
#define CVT_BLKS 800         // k_prep: blocks doing fcw cvt (1638400 / (256*8))

typedef short short8 __attribute__((ext_vector_type(8)));
typedef float f32x4  __attribute__((ext_vector_type(4)));
typedef float f32x16 __attribute__((ext_vector_type(16)));

// ---------------------------------------------------------------------------
// K1: fused prep.  blocks [0,800): fcw fp32->bf16.  blocks [800,1056):
// W2T[i][o] = 0.5*(W[2o][i]+W[2o+1][i]).
// ---------------------------------------------------------------------------
__global__ __launch_bounds__(256) void k_prep(const float* __restrict__ W,
                                              const float* __restrict__ fcw,
                                              float* __restrict__ W2T,
                                              __hip_bfloat16* __restrict__ fcw16) {
    int blk = blockIdx.x;
    if (blk < CVT_BLKS) {
        int i = (blk * 256 + threadIdx.x) * 8;
        float4 a = *(const float4*)(fcw + i);
        float4 b = *(const float4*)(fcw + i + 4);
        short8 v;
        __hip_bfloat16* h = (__hip_bfloat16*)&v;
        h[0] = __float2bfloat16(a.x); h[1] = __float2bfloat16(a.y);
        h[2] = __float2bfloat16(a.z); h[3] = __float2bfloat16(a.w);
        h[4] = __float2bfloat16(b.x); h[5] = __float2bfloat16(b.y);
        h[6] = __float2bfloat16(b.z); h[7] = __float2bfloat16(b.w);
        *(short8*)(fcw16 + i) = v;
    } else {
        int idx = (blk - CVT_BLKS) * 256 + threadIdx.x;   // 0..65535
        int o = idx & (D2 - 1);
        int i = idx >> 7;
        W2T[(size_t)i * D2 + o] =
            0.5f * (W[(size_t)(2 * o) * DIN + i] + W[(size_t)(2 * o + 1) * DIN + i]);
    }
}

// ---------------------------------------------------------------------------
// K2a: split-K GEMM for Z.  Zp[ks][b][q][o] = sum_{i in split} W2[o][i]*X[b][i][q]
// grid (BATCH, ZKS) = 1024 blocks. NO LDS: X reads are wave-uniform (L1
// broadcast), W2T reads are lane-coalesced (L2-hot). No barriers.
// ---------------------------------------------------------------------------
__global__ __launch_bounds__(256) void k_z(const float* __restrict__ X,
                                           const float* __restrict__ W2T,
                                           float* __restrict__ Zp) {
    int b  = blockIdx.x;
    int ks = blockIdx.y;
    int t  = threadIdx.x;
    int o  = t & (D2 - 1);
    int qh = (t >> 7) * 8;   // 0 or 8 (wave-uniform)

    const float* xp = X + ((size_t)b * DIN + (size_t)ks * ZKL) * NQ + qh;
    const float* wp = W2T + (size_t)ks * ZKL * D2 + o;

    float acc[8] = {};
    #pragma unroll 4
    for (int i = 0; i < ZKL; ++i) {
        float  w  = wp[(size_t)i * D2];                 // coalesced, L2-hot
        float4 x0 = *(const float4*)(xp + i * NQ);      // wave-uniform, L1
        float4 x1 = *(const float4*)(xp + i * NQ + 4);
        acc[0] = fmaf(w, x0.x, acc[0]); acc[1] = fmaf(w, x0.y, acc[1]);
        acc[2] = fmaf(w, x0.z, acc[2]); acc[3] = fmaf(w, x0.w, acc[3]);
        acc[4] = fmaf(w, x1.x, acc[4]); acc[5] = fmaf(w, x1.y, acc[5]);
        acc[6] = fmaf(w, x1.z, acc[6]); acc[7] = fmaf(w, x1.w, acc[7]);
    }

    float* zp = Zp + ((size_t)(ks * BATCH + b) * NQ) * D2;
    #pragma unroll
    for (int j = 0; j < 8; ++j)
        zp[(size_t)(qh + j) * D2 + o] = acc[j];          // coalesced per q
}

// ---------------------------------------------------------------------------
// Hand-unrolled Gauss-Jordan step (all indices compile-time constant).
// Lane t<64: r = t&15 (row), cg = t>>4 (col group of 8), g[8] = tableau row.
// ---------------------------------------------------------------------------
#define GJ_STEP(K) do {                                                   \
    float piv = __shfl(g[(K) & 7], ((K) >> 3) * 16 + (K), 64);            \
    float fac = __shfl(g[(K) & 7], ((K) >> 3) * 16 + r, 64);              \
    float inv = 1.0f / piv;                                               \
    float f   = fac * inv;                                                \
    float p0 = __shfl(g[0], cg16 + (K), 64);                              \
    float p1 = __shfl(g[1], cg16 + (K), 64);                              \
    float p2 = __shfl(g[2], cg16 + (K), 64);                              \
    float p3 = __shfl(g[3], cg16 + (K), 64);                              \
    float p4 = __shfl(g[4], cg16 + (K), 64);                              \
    float p5 = __shfl(g[5], cg16 + (K), 64);                              \
    float p6 = __shfl(g[6], cg16 + (K), 64);                              \
    float p7 = __shfl(g[7], cg16 + (K), 64);                              \
    bool isk = (r == (K));                                                \
    g[0] = isk ? p0 * inv : fmaf(-f, p0, g[0]);                           \
    g[1] = isk ? p1 * inv : fmaf(-f, p1, g[1]);                           \
    g[2] = isk ? p2 * inv : fmaf(-f, p2, g[2]);                           \
    g[3] = isk ? p3 * inv : fmaf(-f, p3, g[3]);                           \
    g[4] = isk ? p4 * inv : fmaf(-f, p4, g[4]);                           \
    g[5] = isk ? p5 * inv : fmaf(-f, p5, g[5]);                           \
    g[6] = isk ? p6 * inv : fmaf(-f, p6, g[6]);                           \
    g[7] = isk ? p7 * inv : fmaf(-f, p7, g[7]);                           \
} while (0)

// ---------------------------------------------------------------------------
// K2b: per-batch epilogue, 512 threads.
// Z = sum Zp; G = Z^T Z (fp32); G^{-1} wave-GJ; E = Z G^{-1} (fp32);
// P2 = E^T-by-Z product via MFMA 32x32x16 bf16 (16 tiles, 8 waves x 2).
// ---------------------------------------------------------------------------
__global__ __launch_bounds__(512) void k_gep(const float* __restrict__ Zp,
                                             __hip_bfloat16* __restrict__ P2) {
    __shared__ float Zt[NQ][ZPAD];    // Zt[q][o]
    __shared__ float Et[NQ][ZPAD];    // Et[q][o]
    __shared__ float Gi[NQ][36];      // [G | I] -> right half becomes G^{-1}

    int b = blockIdx.x;
    int t = threadIdx.x;

    // phase 1: reduce the ZKS partials (2048 floats = 512 float4, 1/thread)
    {
        const size_t s4 = (size_t)BATCH * NQ * D2 / 4;   // float4 per split
        const float4* zp = (const float4*)(Zp + ((size_t)b * NQ) * D2);
        float4 a0 = zp[t];
        float4 a1 = zp[t + s4];
        float4 a2 = zp[t + 2 * s4];
        float4 a3 = zp[t + 3 * s4];
        float4 s;
        s.x = (a0.x + a1.x) + (a2.x + a3.x);
        s.y = (a0.y + a1.y) + (a2.y + a3.y);
        s.z = (a0.z + a1.z) + (a2.z + a3.z);
        s.w = (a0.w + a1.w) + (a2.w + a3.w);
        int idx = t * 4;
        *(float4*)&Zt[idx >> 7][idx & (D2 - 1)] = s;
    }
    __syncthreads();

    // phase G: threads 0..255 compute G = Z^T Z, set up [G | I]
    if (t < 256) {
        int qq = t >> 4, rr = t & 15;
        float s = 0.f;
        for (int i = 0; i < D2; i += 4) {
            float4 a = *(const float4*)&Zt[qq][i];
            float4 c = *(const float4*)&Zt[rr][i];
            s = fmaf(a.x, c.x, s); s = fmaf(a.y, c.y, s);
            s = fmaf(a.z, c.z, s); s = fmaf(a.w, c.w, s);
        }
        Gi[qq][rr] = s;
        Gi[qq][NQ + rr] = (qq == rr) ? 1.f : 0.f;
    }
    __syncthreads();

    // phase GJ: wave 0 only, registers + shuffles, fully static.
    if (t < 64) {
        int r    = t & 15;
        int cg   = t >> 4;
        int cg16 = cg * 16;
        float g[8];
        #pragma unroll
        for (int j = 0; j < 8; ++j) g[j] = Gi[r][cg * 8 + j];
        GJ_STEP(0);  GJ_STEP(1);  GJ_STEP(2);  GJ_STEP(3);
        GJ_STEP(4);  GJ_STEP(5);  GJ_STEP(6);  GJ_STEP(7);
        GJ_STEP(8);  GJ_STEP(9);  GJ_STEP(10); GJ_STEP(11);
        GJ_STEP(12); GJ_STEP(13); GJ_STEP(14); GJ_STEP(15);
        if (cg >= 2) {   // write back G^{-1} (cols 16..31)
            #pragma unroll
            for (int j = 0; j < 8; ++j) Gi[r][cg * 8 + j] = g[j];
        }
    }
    __syncthreads();

    // phase E: E = Z G^{-1}, q-major fp32. Thread -> (o, 4 q's).
    {
        int o  = t & (D2 - 1);
        int qg = (t >> 7) * 4;     // 0,4,8,12
        float acc[4] = {};
        #pragma unroll
        for (int rp = 0; rp < NQ; ++rp) {
            float z = Zt[rp][o];                       // contiguous b32
            #pragma unroll
            for (int j = 0; j < 4; ++j)
                acc[j] = fmaf(z, Gi[rp][NQ + qg + j], acc[j]);   // broadcast
        }
        #pragma unroll
        for (int j = 0; j < 4; ++j) Et[qg + j][o] = acc[j];
    }
    __syncthreads();

    // phase P2 (MFMA): P2[i][j] = sum_r Et[r][i] * Zt[r][j].
    // 16 tiles of 32x32 (K=16); wave wv -> tile row wv>>1, tile cols (wv&1)*2..+1.
    // A-frag lane l: A[i = ti*32 + (l&31)][k = (l>>5)*8 + j] = Et[k][i]
    // B-frag lane l: B[k][jcol = tj*32 + (l&31)]             = Zt[k][jcol]
    // C lane l, reg: row = (reg&3) + 8*(reg>>2) + 4*(l>>5), col = l&31.
    {
        __hip_bfloat16* P2b = P2 + (size_t)b * KFC;
        int l  = t & 63;
        int wv = t >> 6;            // 0..7
        int ti = wv >> 1;           // 0..3
        int tj0 = (wv & 1) * 2;     // 0 or 2
        int r8 = (l >> 5) * 8;      // k-offset: 0 or 8
        int rm = l & 31;

        short8 afr;
        {
            __hip_bfloat16* ah = (__hip_bfloat16*)&afr;
            #pragma unroll
            for (int j = 0; j < 8; ++j)
                ah[j] = __float2bfloat16(Et[r8 + j][ti * 32 + rm]);
        }
        #pragma unroll
        for (int tjo = 0; tjo < 2; ++tjo) {
            int tj = tj0 + tjo;
            short8 bfr;
            __hip_bfloat16* bh = (__hip_bfloat16*)&bfr;
            #pragma unroll
            for (int j = 0; j < 8; ++j)
                bh[j] = __float2bfloat16(Zt[r8 + j][tj * 32 + rm]);
            f32x16 cc = {};
            cc = __builtin_amdgcn_mfma_f32_32x32x16_bf16(afr, bfr, cc, 0, 0, 0);
            #pragma unroll
            for (int reg = 0; reg < 16; ++reg) {
                int row = (reg & 3) + 8 * (reg >> 2) + 4 * (l >> 5);
                P2b[(size_t)(ti * 32 + row) * D2 + tj * 32 + rm] =
                    __float2bfloat16(cc[reg]);
            }
        }
    }
}

// ---------------------------------------------------------------------------
// K3: MFMA split-K FC.  part[ks][b][c] = sum_{k in chunk} P2[b][k]*fcw[c][k]
// grid (16 bt, 32 ks) = 512 blocks -> 2 blocks/CU.
// ---------------------------------------------------------------------------
__global__ __launch_bounds__(256) void k_fc(const __hip_bfloat16* __restrict__ P2,
                                            const __hip_bfloat16* __restrict__ fcw16,
                                            float* __restrict__ part) {
    int bt = blockIdx.x;            // 0..15
    int ks = blockIdx.y;            // 0..31
    int t  = threadIdx.x;
    int lane = t & 63;
    int w    = t >> 6;
    int m  = lane & 15;
    int kg = (lane >> 4) * 8;

    const __hip_bfloat16* pa =
        P2 + (size_t)(bt * 16 + m) * KFC + ks * KCH + kg;

    int c0 = w * 32 + m;
    int c1 = c0 + 16;
    bool v0 = (c0 < NC), v1 = (c1 < NC);
    const __hip_bfloat16* pb0 =
        fcw16 + (size_t)(v0 ? c0 : 0) * KFC + ks * KCH + kg;
    const __hip_bfloat16* pb1 =
        fcw16 + (size_t)(v1 ? c1 : 0) * KFC + ks * KCH + kg;

    f32x4 acc0 = {0.f, 0.f, 0.f, 0.f};
    f32x4 acc1 = {0.f, 0.f, 0.f, 0.f};
    short8 zz = {};

    #pragma unroll 4
    for (int s = 0; s < STEPS; ++s) {
        short8 a  = *(const short8*)(pa + s * 32);
        short8 b0 = v0 ? *(const short8*)(pb0 + s * 32) : zz;
        short8 b1 = v1 ? *(const short8*)(pb1 + s * 32) : zz;
        acc0 = __builtin_amdgcn_mfma_f32_16x16x32_bf16(a, b0, acc0, 0, 0, 0);
        acc1 = __builtin_amdgcn_mfma_f32_16x16x32_bf16(a, b1, acc1, 0, 0, 0);
    }

    int r0 = (lane >> 4) * 4;
    float* pp = part + ((size_t)ks * BATCH + bt * 16 + r0) * D2;
    #pragma unroll
    for (int j = 0; j < 4; ++j) {
        pp[(size_t)j * D2 + w * 32 + m]      = acc0[j];
        pp[(size_t)j * D2 + w * 32 + 16 + m] = acc1[j];
    }
}

// ---------------------------------------------------------------------------
// K4: out[b][c] = fcb[c] + sum_ks part[ks][b][c]
// ---------------------------------------------------------------------------
__global__ __launch_bounds__(128) void k_red(const float* __restrict__ part,
                                             const float* __restrict__ fcb,
                                             float* __restrict__ out) {
    int b = blockIdx.x;
    int c = threadIdx.x;
    if (c < NC) {
        float s = fcb[c];
        #pragma unroll 8
        for (int ks = 0; ks < KS; ++ks)
            s += part[((size_t)ks * BATCH + b) * D2 + c];
        out[(size_t)b * NC + c] = s;
    }
}

extern "C" void kernel_launch(void* const* d_in, const int* in_sizes, int n_in,
                              void* d_out, int out_size, void* d_ws, size_t ws_size,
                              hipStream_t stream) {
    const float* X   = (const float*)d_in[0];   // (256, 512, 16)
    const float* W   = (const float*)d_in[1];   // (256, 512)
    const float* fcw = (const float*)d_in[2];   // (100, 16384)
    const float* fcb = (const float*)d_in[3];   // (100,)
    float* out = (float*)d_out;                 // (256, 100)

    float* ws = (float*)d_ws;
    float*          W2T   = ws;                                   // 65536 f
    float*          Zp    = ws + 65536;                           // 2097152 f (8 MB)
    float*          part  = Zp;                                   // aliased: Zp dead after k_gep
    __hip_bfloat16* P2b16 = (__hip_bfloat16*)(ws + 65536 + 2097152);            // 4194304 bf16
    __hip_bfloat16* fcw16 = (__hip_bfloat16*)(ws + 65536 + 2097152 + 2097152);  // 1638400 bf16
    // total ws ~= 19.4 MB

    k_prep<<<dim3(CVT_BLKS + 256), 256, 0, stream>>>(W, fcw, W2T, fcw16);
    k_z   <<<dim3(BATCH, ZKS), 256, 0, stream>>>(X, W2T, Zp);
    k_gep <<<dim3(BATCH), 512, 0, stream>>>(Zp, P2b16);
    k_fc  <<<dim3(16, KS), 256, 0, stream>>>(P2b16, fcw16, part);
    k_red <<<dim3(BATCH), 128, 0, stream>>>(part, fcb, out);
}

// Round 8
// 41.421 us; speedup vs baseline: 1.6599x; 1.6599x over previous
//
#include <hip/hip_runtime.h>
#include <hip/hip_bf16.h>
#include <cstdint>

#define BATCH 256
#define DIN   512
#define D2    128
#define NQ    16
#define NC    100
#define KFC   (D2 * D2)      // 16384

#define KS    32             // K-splits for FC
#define KCH   (KFC / KS)     // 512
#define STEPS (KCH / 32)     // 16 MFMA K-steps per block

#define ZPAD  132            // Zt/Et row stride (floats)
#define XTP   520            // Xt LDS row stride (bf16): 1040 B, 16B-aligned, conflict-optimal
#define CVT_BLKS 800         // k_prep: blocks doing fcw cvt
#define W2_BLKS  256         // k_prep: blocks doing W2 hi/lo gen (65536 elems)

typedef short short8 __attribute__((ext_vector_type(8)));
typedef float f32x4  __attribute__((ext_vector_type(4)));
typedef float f32x16 __attribute__((ext_vector_type(16)));

// ---------------------------------------------------------------------------
// K1: fused prep. blocks [0,800): fcw fp32->bf16.
// blocks [800,1056): W2 = row-pair-avg of W, split into bf16 hi/lo, [o][i].
// ---------------------------------------------------------------------------
__global__ __launch_bounds__(256) void k_prep(const float* __restrict__ W,
                                              const float* __restrict__ fcw,
                                              __hip_bfloat16* __restrict__ W2hi,
                                              __hip_bfloat16* __restrict__ W2lo,
                                              __hip_bfloat16* __restrict__ fcw16) {
    int blk = blockIdx.x;
    if (blk < CVT_BLKS) {
        int i = (blk * 256 + threadIdx.x) * 8;
        float4 a = *(const float4*)(fcw + i);
        float4 b = *(const float4*)(fcw + i + 4);
        short8 v;
        __hip_bfloat16* h = (__hip_bfloat16*)&v;
        h[0] = __float2bfloat16(a.x); h[1] = __float2bfloat16(a.y);
        h[2] = __float2bfloat16(a.z); h[3] = __float2bfloat16(a.w);
        h[4] = __float2bfloat16(b.x); h[5] = __float2bfloat16(b.y);
        h[6] = __float2bfloat16(b.z); h[7] = __float2bfloat16(b.w);
        *(short8*)(fcw16 + i) = v;
    } else {
        int idx = (blk - CVT_BLKS) * 256 + threadIdx.x;   // 0..65535
        int o = idx >> 9;          // 0..127
        int i = idx & (DIN - 1);   // 0..511
        float v = 0.5f * (W[(size_t)(2 * o) * DIN + i] +
                          W[(size_t)(2 * o + 1) * DIN + i]);
        __hip_bfloat16 hi = __float2bfloat16(v);
        __hip_bfloat16 lo = __float2bfloat16(v - __bfloat162float(hi));
        W2hi[idx] = hi;            // idx == o*512 + i
        W2lo[idx] = lo;
    }
}

// ---------------------------------------------------------------------------
// Hand-unrolled Gauss-Jordan step (all indices compile-time constant).
// Lane t<64: r = t&15 (row), cg = t>>4 (col group of 8), g[8] = tableau row.
// ---------------------------------------------------------------------------
#define GJ_STEP(K) do {                                                   \
    float piv = __shfl(g[(K) & 7], ((K) >> 3) * 16 + (K), 64);            \
    float fac = __shfl(g[(K) & 7], ((K) >> 3) * 16 + r, 64);              \
    float inv = 1.0f / piv;                                               \
    float f   = fac * inv;                                                \
    float p0 = __shfl(g[0], cg16 + (K), 64);                              \
    float p1 = __shfl(g[1], cg16 + (K), 64);                              \
    float p2 = __shfl(g[2], cg16 + (K), 64);                              \
    float p3 = __shfl(g[3], cg16 + (K), 64);                              \
    float p4 = __shfl(g[4], cg16 + (K), 64);                              \
    float p5 = __shfl(g[5], cg16 + (K), 64);                              \
    float p6 = __shfl(g[6], cg16 + (K), 64);                              \
    float p7 = __shfl(g[7], cg16 + (K), 64);                              \
    bool isk = (r == (K));                                                \
    g[0] = isk ? p0 * inv : fmaf(-f, p0, g[0]);                           \
    g[1] = isk ? p1 * inv : fmaf(-f, p1, g[1]);                           \
    g[2] = isk ? p2 * inv : fmaf(-f, p2, g[2]);                           \
    g[3] = isk ? p3 * inv : fmaf(-f, p3, g[3]);                           \
    g[4] = isk ? p4 * inv : fmaf(-f, p4, g[4]);                           \
    g[5] = isk ? p5 * inv : fmaf(-f, p5, g[5]);                           \
    g[6] = isk ? p6 * inv : fmaf(-f, p6, g[6]);                           \
    g[7] = isk ? p7 * inv : fmaf(-f, p7, g[7]);                           \
} while (0)

// ---------------------------------------------------------------------------
// K2: full per-batch pipeline, 256 blocks x 512 threads (8 waves).
// stage X_b -> transpose + bf16 hi/lo split (LDS) -> Z via MFMA (hi/lo
// compensated, ~fp32 accurate) -> G = Z^T Z -> wave-register GJ -> E ->
// P2 = E Z^T via MFMA -> bf16 global. W2 reads are L2-hot (256 KB bf16).
// ---------------------------------------------------------------------------
__global__ __launch_bounds__(512) void k_zgep(const float* __restrict__ X,
                                              const __hip_bfloat16* __restrict__ W2hi,
                                              const __hip_bfloat16* __restrict__ W2lo,
                                              __hip_bfloat16* __restrict__ P2) {
    __shared__ float Xs[DIN][17];               // 34.8 KB, pad 17 vs transpose reads
    __shared__ __hip_bfloat16 Xthi[NQ][XTP];    // 16.6 KB
    __shared__ __hip_bfloat16 Xtlo[NQ][XTP];    // 16.6 KB
    __shared__ float Zt[NQ][ZPAD];              // Zt[q][o]
    __shared__ float Et[NQ][ZPAD];
    __shared__ float Gi[NQ][36];                // [G | I] -> right half = G^{-1}

    int b = blockIdx.x;
    int t = threadIdx.x;
    int l = t & 63;
    int wv = t >> 6;                            // 0..7

    // phase 0: stage X_b (8192 f) -- coalesced float4 reads, scalar LDS scatter
    {
        const float4* src = (const float4*)(X + (size_t)b * DIN * NQ);
        #pragma unroll
        for (int r = 0; r < 4; ++r) {
            float4 v = src[t + r * 512];
            int idx = (t + r * 512) * 4;
            int i = idx >> 4, q = idx & 15;     // q in {0,4,8,12}
            Xs[i][q]     = v.x;
            Xs[i][q + 1] = v.y;
            Xs[i][q + 2] = v.z;
            Xs[i][q + 3] = v.w;
        }
    }
    __syncthreads();

    // phase 0b: transpose + hi/lo split -> Xthi/Xtlo[q][i]
    {
        int q  = t >> 5;        // 0..15
        int li = t & 31;        // 0..31
        #pragma unroll
        for (int c = 0; c < 8; ++c) {
            int i0 = c * 64 + li * 2;
            float v0 = Xs[i0][q], v1 = Xs[i0 + 1][q];     // banks 2li+q: 2-way
            __hip_bfloat16 h0 = __float2bfloat16(v0);
            __hip_bfloat16 h1 = __float2bfloat16(v1);
            __hip_bfloat16 l0 = __float2bfloat16(v0 - __bfloat162float(h0));
            __hip_bfloat16 l1 = __float2bfloat16(v1 - __bfloat162float(h1));
            Xthi[q][i0] = h0; Xthi[q][i0 + 1] = h1;       // paired dword writes
            Xtlo[q][i0] = l0; Xtlo[q][i0 + 1] = l1;
        }
    }
    __syncthreads();

    // phase Z (MFMA): wave wv -> rows wv*16..+15, all 16 q, K=512.
    // Z = W2hi*Xhi + W2hi*Xlo + W2lo*Xhi  (lo*lo dropped: ~2^-18 rel err)
    {
        int m  = l & 15;
        int kg = (l >> 4) * 8;
        const __hip_bfloat16* whi = W2hi + (size_t)(wv * 16 + m) * DIN + kg;
        const __hip_bfloat16* wlo = W2lo + (size_t)(wv * 16 + m) * DIN + kg;
        f32x4 acc = {0.f, 0.f, 0.f, 0.f};
        #pragma unroll 4
        for (int s = 0; s < 16; ++s) {
            short8 ahi = *(const short8*)(whi + s * 32);
            short8 alo = *(const short8*)(wlo + s * 32);
            short8 bhi = *(const short8*)&Xthi[m][s * 32 + kg];
            short8 blo = *(const short8*)&Xtlo[m][s * 32 + kg];
            acc = __builtin_amdgcn_mfma_f32_16x16x32_bf16(ahi, bhi, acc, 0, 0, 0);
            acc = __builtin_amdgcn_mfma_f32_16x16x32_bf16(ahi, blo, acc, 0, 0, 0);
            acc = __builtin_amdgcn_mfma_f32_16x16x32_bf16(alo, bhi, acc, 0, 0, 0);
        }
        // C layout: col(q) = l&15, row = (l>>4)*4 + j  ->  Zt[q][wv*16+row]
        int r0 = (l >> 4) * 4;
        #pragma unroll
        for (int j = 0; j < 4; ++j)
            Zt[m][wv * 16 + r0 + j] = acc[j];
    }
    __syncthreads();

    // phase G: threads 0..255 compute G = Z^T Z, set up [G | I]
    if (t < 256) {
        int qq = t >> 4, rr = t & 15;
        float s = 0.f;
        for (int i = 0; i < D2; i += 4) {
            float4 a = *(const float4*)&Zt[qq][i];
            float4 c = *(const float4*)&Zt[rr][i];
            s = fmaf(a.x, c.x, s); s = fmaf(a.y, c.y, s);
            s = fmaf(a.z, c.z, s); s = fmaf(a.w, c.w, s);
        }
        Gi[qq][rr] = s;
        Gi[qq][NQ + rr] = (qq == rr) ? 1.f : 0.f;
    }
    __syncthreads();

    // phase GJ: wave 0 only, registers + shuffles, fully static.
    if (t < 64) {
        int r    = t & 15;
        int cg   = t >> 4;
        int cg16 = cg * 16;
        float g[8];
        #pragma unroll
        for (int j = 0; j < 8; ++j) g[j] = Gi[r][cg * 8 + j];
        GJ_STEP(0);  GJ_STEP(1);  GJ_STEP(2);  GJ_STEP(3);
        GJ_STEP(4);  GJ_STEP(5);  GJ_STEP(6);  GJ_STEP(7);
        GJ_STEP(8);  GJ_STEP(9);  GJ_STEP(10); GJ_STEP(11);
        GJ_STEP(12); GJ_STEP(13); GJ_STEP(14); GJ_STEP(15);
        if (cg >= 2) {   // write back G^{-1} (cols 16..31)
            #pragma unroll
            for (int j = 0; j < 8; ++j) Gi[r][cg * 8 + j] = g[j];
        }
    }
    __syncthreads();

    // phase E: E = Z G^{-1}, q-major fp32. Thread -> (o, 4 q's).
    {
        int o  = t & (D2 - 1);
        int qg = (t >> 7) * 4;     // 0,4,8,12
        float acc[4] = {};
        #pragma unroll
        for (int rp = 0; rp < NQ; ++rp) {
            float z = Zt[rp][o];
            #pragma unroll
            for (int j = 0; j < 4; ++j)
                acc[j] = fmaf(z, Gi[rp][NQ + qg + j], acc[j]);
        }
        #pragma unroll
        for (int j = 0; j < 4; ++j) Et[qg + j][o] = acc[j];
    }
    __syncthreads();

    // phase P2 (MFMA): P2[i][j] = sum_r Et[r][i] * Zt[r][j].
    // 16 tiles of 32x32 (K=16); wave wv -> tile row wv>>1, cols (wv&1)*2..+1.
    {
        __hip_bfloat16* P2b = P2 + (size_t)b * KFC;
        int ti = wv >> 1;           // 0..3
        int tj0 = (wv & 1) * 2;     // 0 or 2
        int r8 = (l >> 5) * 8;      // k-offset: 0 or 8
        int rm = l & 31;

        short8 afr;
        {
            __hip_bfloat16* ah = (__hip_bfloat16*)&afr;
            #pragma unroll
            for (int j = 0; j < 8; ++j)
                ah[j] = __float2bfloat16(Et[r8 + j][ti * 32 + rm]);
        }
        #pragma unroll
        for (int tjo = 0; tjo < 2; ++tjo) {
            int tj = tj0 + tjo;
            short8 bfr;
            __hip_bfloat16* bh = (__hip_bfloat16*)&bfr;
            #pragma unroll
            for (int j = 0; j < 8; ++j)
                bh[j] = __float2bfloat16(Zt[r8 + j][tj * 32 + rm]);
            f32x16 cc = {};
            cc = __builtin_amdgcn_mfma_f32_32x32x16_bf16(afr, bfr, cc, 0, 0, 0);
            #pragma unroll
            for (int reg = 0; reg < 16; ++reg) {
                int row = (reg & 3) + 8 * (reg >> 2) + 4 * (l >> 5);
                P2b[(size_t)(ti * 32 + row) * D2 + tj * 32 + rm] =
                    __float2bfloat16(cc[reg]);
            }
        }
    }
}

// ---------------------------------------------------------------------------
// K3: MFMA split-K FC.  part[ks][b][c] = sum_{k in chunk} P2[b][k]*fcw[c][k]
// grid (16 bt, 32 ks) = 512 blocks.
// ---------------------------------------------------------------------------
__global__ __launch_bounds__(256) void k_fc(const __hip_bfloat16* __restrict__ P2,
                                            const __hip_bfloat16* __restrict__ fcw16,
                                            float* __restrict__ part) {
    int bt = blockIdx.x;            // 0..15
    int ks = blockIdx.y;            // 0..31
    int t  = threadIdx.x;
    int lane = t & 63;
    int w    = t >> 6;
    int m  = lane & 15;
    int kg = (lane >> 4) * 8;

    const __hip_bfloat16* pa =
        P2 + (size_t)(bt * 16 + m) * KFC + ks * KCH + kg;

    int c0 = w * 32 + m;
    int c1 = c0 + 16;
    bool v0 = (c0 < NC), v1 = (c1 < NC);
    const __hip_bfloat16* pb0 =
        fcw16 + (size_t)(v0 ? c0 : 0) * KFC + ks * KCH + kg;
    const __hip_bfloat16* pb1 =
        fcw16 + (size_t)(v1 ? c1 : 0) * KFC + ks * KCH + kg;

    f32x4 acc0 = {0.f, 0.f, 0.f, 0.f};
    f32x4 acc1 = {0.f, 0.f, 0.f, 0.f};
    short8 zz = {};

    #pragma unroll 4
    for (int s = 0; s < STEPS; ++s) {
        short8 a  = *(const short8*)(pa + s * 32);
        short8 b0 = v0 ? *(const short8*)(pb0 + s * 32) : zz;
        short8 b1 = v1 ? *(const short8*)(pb1 + s * 32) : zz;
        acc0 = __builtin_amdgcn_mfma_f32_16x16x32_bf16(a, b0, acc0, 0, 0, 0);
        acc1 = __builtin_amdgcn_mfma_f32_16x16x32_bf16(a, b1, acc1, 0, 0, 0);
    }

    int r0 = (lane >> 4) * 4;
    float* pp = part + ((size_t)ks * BATCH + bt * 16 + r0) * D2;
    #pragma unroll
    for (int j = 0; j < 4; ++j) {
        pp[(size_t)j * D2 + w * 32 + m]      = acc0[j];
        pp[(size_t)j * D2 + w * 32 + 16 + m] = acc1[j];
    }
}

// ---------------------------------------------------------------------------
// K4: out[b][c] = fcb[c] + sum_ks part[ks][b][c]
// ---------------------------------------------------------------------------
__global__ __launch_bounds__(128) void k_red(const float* __restrict__ part,
                                             const float* __restrict__ fcb,
                                             float* __restrict__ out) {
    int b = blockIdx.x;
    int c = threadIdx.x;
    if (c < NC) {
        float s = fcb[c];
        #pragma unroll 8
        for (int ks = 0; ks < KS; ++ks)
            s += part[((size_t)ks * BATCH + b) * D2 + c];
        out[(size_t)b * NC + c] = s;
    }
}

extern "C" void kernel_launch(void* const* d_in, const int* in_sizes, int n_in,
                              void* d_out, int out_size, void* d_ws, size_t ws_size,
                              hipStream_t stream) {
    const float* X   = (const float*)d_in[0];   // (256, 512, 16)
    const float* W   = (const float*)d_in[1];   // (256, 512)
    const float* fcw = (const float*)d_in[2];   // (100, 16384)
    const float* fcb = (const float*)d_in[3];   // (100,)
    float* out = (float*)d_out;                 // (256, 100)

    __hip_bfloat16* W2hi  = (__hip_bfloat16*)d_ws;            // 65536 bf16
    __hip_bfloat16* W2lo  = W2hi + 65536;                     // 65536 bf16
    __hip_bfloat16* fcw16 = W2lo + 65536;                     // 1638400 bf16
    __hip_bfloat16* P2b16 = fcw16 + 1638400;                  // 4194304 bf16
    float*          part  = (float*)(P2b16 + 4194304);        // 1048576 f
    // total ws ~= 16.1 MB

    k_prep<<<dim3(CVT_BLKS + W2_BLKS), 256, 0, stream>>>(W, fcw, W2hi, W2lo, fcw16);
    k_zgep<<<dim3(BATCH), 512, 0, stream>>>(X, W2hi, W2lo, P2b16);
    k_fc  <<<dim3(16, KS), 256, 0, stream>>>(P2b16, fcw16, part);
    k_red <<<dim3(BATCH), 128, 0, stream>>>(part, fcb, out);
}